// Round 1
// baseline (491.114 us; speedup 1.0000x reference)
//
#include <hip/hip_runtime.h>

#define BATCH 2048
#define NF 512
#define FD 64

// Dependency-tree slot tables (ints, stored at base of d_ws):
// stage s has C[s] slots; T_s[i] = fold id of slot i.
// C = {128, 64, 32, 16, 8} for stages 0..4 (stage 0 indexes in_graph).
#define T4_OFF 0
#define T3_OFF 8
#define T2_OFF 24
#define T1_OFF 56
#define T0_OFF 120

__global__ void build_tree_kernel(const int* __restrict__ fold_idx,
                                  const int* __restrict__ out_idx,
                                  int* __restrict__ tree) {
  if (threadIdx.x != 0 || blockIdx.x != 0) return;
  int* T4 = tree + T4_OFF;
  int* T3 = tree + T3_OFF;
  int* T2 = tree + T2_OFF;
  int* T1 = tree + T1_OFF;
  int* T0 = tree + T0_OFF;
  for (int i = 0; i < 8; ++i) T4[i] = out_idx[i];
  for (int i = 0; i < 8; ++i) {
    int f = T4[i];
    T3[2*i]   = fold_idx[(3*NF + f)*2 + 0];
    T3[2*i+1] = fold_idx[(3*NF + f)*2 + 1];
  }
  for (int i = 0; i < 16; ++i) {
    int f = T3[i];
    T2[2*i]   = fold_idx[(2*NF + f)*2 + 0];
    T2[2*i+1] = fold_idx[(2*NF + f)*2 + 1];
  }
  for (int i = 0; i < 32; ++i) {
    int f = T2[i];
    T1[2*i]   = fold_idx[(1*NF + f)*2 + 0];
    T1[2*i+1] = fold_idx[(1*NF + f)*2 + 1];
  }
  for (int i = 0; i < 64; ++i) {
    int f = T1[i];
    T0[2*i]   = fold_idx[(0*NF + f)*2 + 0];
    T0[2*i+1] = fold_idx[(0*NF + f)*2 + 1];
  }
}

// One wave (64 lanes) per (node, batch-tile-of-64). lane = batch row.
// W addresses are wave-uniform -> scalar-cache s_load (hopefully).
// Intermediates stored transposed [slot][k][b] for coalesced access.
template<int LAYER, int TOUT_OFF, bool FIRST, bool LAST>
__global__ __launch_bounds__(64) void stage_kernel(
    const float* __restrict__ xin,
    const float* __restrict__ weights,
    const int* __restrict__ tree,
    float* __restrict__ out) {
  const int node = blockIdx.x >> 5;                  // slot at output stage
  const int b    = (blockIdx.x & 31) * 64 + threadIdx.x;
  const int fold = __builtin_amdgcn_readfirstlane(tree[TOUT_OFF + node]);
  const float* __restrict__ W =
      weights + (size_t)(LAYER * NF + fold) * (FD * FD);

  float acc[FD];
  #pragma unroll
  for (int j = 0; j < FD; ++j) acc[j] = 0.0f;

  if (FIRST) {
    // parents come from in_graph, layout [b][fold][k] -> per-lane float4 rows
    const int f0 = __builtin_amdgcn_readfirstlane(tree[T0_OFF + 2*node]);
    const int f1 = __builtin_amdgcn_readfirstlane(tree[T0_OFF + 2*node + 1]);
    const float4* __restrict__ p0 =
        (const float4*)(xin + ((size_t)b * NF + f0) * FD);
    const float4* __restrict__ p1 =
        (const float4*)(xin + ((size_t)b * NF + f1) * FD);
    for (int kk = 0; kk < FD / 4; ++kk) {
      float4 a = p0[kk];
      float4 c = p1[kk];
      float h0 = a.x * c.x, h1 = a.y * c.y, h2 = a.z * c.z, h3 = a.w * c.w;
      const float* __restrict__ Wk = W + kk * 4 * FD;
      #pragma unroll
      for (int j = 0; j < FD; ++j) {
        acc[j] = fmaf(h0, Wk[j],          acc[j]);
        acc[j] = fmaf(h1, Wk[FD + j],     acc[j]);
        acc[j] = fmaf(h2, Wk[2*FD + j],   acc[j]);
        acc[j] = fmaf(h3, Wk[3*FD + j],   acc[j]);
      }
    }
  } else {
    // parents from transposed workspace [slot][k][b] -> coalesced b32 loads
    const float* __restrict__ p0 = xin + (size_t)(2*node)     * FD * BATCH + b;
    const float* __restrict__ p1 = xin + (size_t)(2*node + 1) * FD * BATCH + b;
    for (int kk = 0; kk < FD; kk += 4) {
      float h0 = p0[(kk+0)*BATCH] * p1[(kk+0)*BATCH];
      float h1 = p0[(kk+1)*BATCH] * p1[(kk+1)*BATCH];
      float h2 = p0[(kk+2)*BATCH] * p1[(kk+2)*BATCH];
      float h3 = p0[(kk+3)*BATCH] * p1[(kk+3)*BATCH];
      const float* __restrict__ Wk = W + kk * FD;
      #pragma unroll
      for (int j = 0; j < FD; ++j) {
        acc[j] = fmaf(h0, Wk[j],          acc[j]);
        acc[j] = fmaf(h1, Wk[FD + j],     acc[j]);
        acc[j] = fmaf(h2, Wk[2*FD + j],   acc[j]);
        acc[j] = fmaf(h3, Wk[3*FD + j],   acc[j]);
      }
    }
  }

  if (LAST) {
    // final output layout [b][out_slot][j] (fp32), per-lane contiguous row
    float* __restrict__ o = out + ((size_t)b * 8 + node) * FD;
    #pragma unroll
    for (int j = 0; j < FD; ++j) o[j] = acc[j];
  } else {
    // transposed workspace [slot][j][b], coalesced stores
    float* __restrict__ o = out + (size_t)node * FD * BATCH + b;
    #pragma unroll
    for (int j = 0; j < FD; ++j) o[j * BATCH] = acc[j];
  }
}

extern "C" void kernel_launch(void* const* d_in, const int* in_sizes, int n_in,
                              void* d_out, int out_size, void* d_ws, size_t ws_size,
                              hipStream_t stream) {
  const float* in_graph = (const float*)d_in[0];
  const float* weights  = (const float*)d_in[1];
  const int*   fold_idx = (const int*)d_in[2];
  const int*   out_idx  = (const int*)d_in[3];
  float* out = (float*)d_out;

  char* ws   = (char*)d_ws;
  int*  tree = (int*)ws;                                    // 248 ints
  float* bufA = (float*)(ws + 4096);                        // 64 slots = 32 MB
  float* bufB = (float*)(ws + 4096 + (size_t)64 * FD * BATCH * 4); // 32 slots = 16 MB

  build_tree_kernel<<<1, 64, 0, stream>>>(fold_idx, out_idx, tree);

  // stage 1: 64 nodes, reads in_graph (T0 folds), writes bufA
  stage_kernel<0, T1_OFF, true,  false><<<dim3(64*32), 64, 0, stream>>>(in_graph, weights, tree, bufA);
  // stage 2: 32 nodes, reads bufA, writes bufB
  stage_kernel<1, T2_OFF, false, false><<<dim3(32*32), 64, 0, stream>>>(bufA, weights, tree, bufB);
  // stage 3: 16 nodes, reads bufB, writes bufA (stage-1 data is dead)
  stage_kernel<2, T3_OFF, false, false><<<dim3(16*32), 64, 0, stream>>>(bufB, weights, tree, bufA);
  // stage 4: 8 nodes, reads bufA, writes d_out
  stage_kernel<3, T4_OFF, false, true ><<<dim3( 8*32), 64, 0, stream>>>(bufA, weights, tree, out);
}

// Round 2
// 392.330 us; speedup vs baseline: 1.2518x; 1.2518x over previous
//
#include <hip/hip_runtime.h>

#define BATCH 2048
#define NF 512
#define FD 64
#define BT 128            // batch rows per block
#define NBT (BATCH / BT)  // 16 batch tiles

// Dependency-tree slot tables (ints, at base of d_ws):
#define T4_OFF 0
#define T3_OFF 8
#define T2_OFF 24
#define T1_OFF 56
#define T0_OFF 120

__global__ void build_tree_kernel(const int* __restrict__ fold_idx,
                                  const int* __restrict__ out_idx,
                                  int* __restrict__ tree) {
  if (threadIdx.x != 0 || blockIdx.x != 0) return;
  int* T4 = tree + T4_OFF;
  int* T3 = tree + T3_OFF;
  int* T2 = tree + T2_OFF;
  int* T1 = tree + T1_OFF;
  int* T0 = tree + T0_OFF;
  for (int i = 0; i < 8; ++i) T4[i] = out_idx[i];
  for (int i = 0; i < 8; ++i) {
    int f = T4[i];
    T3[2*i]   = fold_idx[(3*NF + f)*2 + 0];
    T3[2*i+1] = fold_idx[(3*NF + f)*2 + 1];
  }
  for (int i = 0; i < 16; ++i) {
    int f = T3[i];
    T2[2*i]   = fold_idx[(2*NF + f)*2 + 0];
    T2[2*i+1] = fold_idx[(2*NF + f)*2 + 1];
  }
  for (int i = 0; i < 32; ++i) {
    int f = T2[i];
    T1[2*i]   = fold_idx[(1*NF + f)*2 + 0];
    T1[2*i+1] = fold_idx[(1*NF + f)*2 + 1];
  }
  for (int i = 0; i < 64; ++i) {
    int f = T1[i];
    T0[2*i]   = fold_idx[(0*NF + f)*2 + 0];
    T0[2*i+1] = fold_idx[(0*NF + f)*2 + 1];
  }
}

// Per node: C[b, j] = sum_k (p0[b,k]*p1[b,k]) * W[k,j]   (2048x64 @ 64x64)
// Block = 256 threads, one (node, 128-batch-tile). W + H staged in LDS.
// Thread tile: 8 b-rows x 4 j-cols in registers.
// Intermediate layout: [slot][b][j] -> all global ld/st are coalesced float4.
template<int LAYER, int TOUT_OFF, bool FIRST, bool LAST>
__global__ __launch_bounds__(256) void stage_kernel(
    const float* __restrict__ xin,
    const float* __restrict__ weights,
    const int* __restrict__ tree,
    float* __restrict__ out) {
  __shared__ float Hs[FD][BT + 1];  // +1 pad: H reads hit 4 distinct banks
  __shared__ float Ws[FD][FD];      // 16 KB

  const int t     = threadIdx.x;
  const int node  = blockIdx.x >> 4;      // NBT = 16
  const int btile = blockIdx.x & (NBT - 1);
  const int B0    = btile * BT;
  const int fold  = tree[TOUT_OFF + node];
  const float* __restrict__ W =
      weights + (size_t)(LAYER * NF + fold) * (FD * FD);

  // ---- stage W: 4096 floats, 16/thread, coalesced float4 both sides ----
  {
    const float4* __restrict__ Wv = (const float4*)W;
    #pragma unroll
    for (int i = 0; i < 4; ++i) {
      int f4 = i * 256 + t;        // 0..1023 float4s
      int k = f4 >> 4;
      int c4 = (f4 & 15) * 4;
      float4 v = Wv[f4];
      *(float4*)&Ws[k][c4] = v;
    }
  }

  // ---- stage H[k][b] = p0[b][k] * p1[b][k] ----
  {
    const int kq  = t & 15;        // which float4 along k
    const int bl0 = t >> 4;        // 0..15
    if (FIRST) {
      const int f0 = tree[T0_OFF + 2*node];
      const int f1 = tree[T0_OFF + 2*node + 1];
      #pragma unroll
      for (int p = 0; p < BT / 16; ++p) {
        int bl = p * 16 + bl0;
        const float* row = xin + ((size_t)(B0 + bl) * NF) * FD + kq * 4;
        float4 a = *(const float4*)(row + (size_t)f0 * FD);
        float4 c = *(const float4*)(row + (size_t)f1 * FD);
        Hs[kq*4+0][bl] = a.x * c.x;
        Hs[kq*4+1][bl] = a.y * c.y;
        Hs[kq*4+2][bl] = a.z * c.z;
        Hs[kq*4+3][bl] = a.w * c.w;
      }
    } else {
      const float* __restrict__ p0 = xin + (size_t)(2*node)   * BATCH * FD;
      const float* __restrict__ p1 = xin + (size_t)(2*node+1) * BATCH * FD;
      #pragma unroll
      for (int p = 0; p < BT / 16; ++p) {
        int bl = p * 16 + bl0;
        size_t off = (size_t)(B0 + bl) * FD + kq * 4;
        float4 a = *(const float4*)(p0 + off);
        float4 c = *(const float4*)(p1 + off);
        Hs[kq*4+0][bl] = a.x * c.x;
        Hs[kq*4+1][bl] = a.y * c.y;
        Hs[kq*4+2][bl] = a.z * c.z;
        Hs[kq*4+3][bl] = a.w * c.w;
      }
    }
  }
  __syncthreads();

  // ---- register-blocked GEMM: thread = 8 rows x 4 cols ----
  const int tx = t & 15;    // j group: cols tx*4 .. tx*4+3
  const int ty = t >> 4;    // b group: rows ty*8 .. ty*8+7
  float acc[8][4];
  #pragma unroll
  for (int r = 0; r < 8; ++r)
    #pragma unroll
    for (int c = 0; c < 4; ++c) acc[r][c] = 0.0f;

  #pragma unroll 2
  for (int k = 0; k < FD; ++k) {
    float4 w = *(const float4*)&Ws[k][tx * 4];
    #pragma unroll
    for (int r = 0; r < 8; ++r) {
      float h = Hs[k][ty * 8 + r];
      acc[r][0] = fmaf(h, w.x, acc[r][0]);
      acc[r][1] = fmaf(h, w.y, acc[r][1]);
      acc[r][2] = fmaf(h, w.z, acc[r][2]);
      acc[r][3] = fmaf(h, w.w, acc[r][3]);
    }
  }

  // ---- store: coalesced float4 ----
  #pragma unroll
  for (int r = 0; r < 8; ++r) {
    float4 v = make_float4(acc[r][0], acc[r][1], acc[r][2], acc[r][3]);
    int b = B0 + ty * 8 + r;
    if (LAST) {
      // final layout [b][out_slot][j]
      *(float4*)(out + ((size_t)b * 8 + node) * FD + tx * 4) = v;
    } else {
      // intermediate layout [slot][b][j]
      *(float4*)(out + ((size_t)node * BATCH + b) * FD + tx * 4) = v;
    }
  }
}

extern "C" void kernel_launch(void* const* d_in, const int* in_sizes, int n_in,
                              void* d_out, int out_size, void* d_ws, size_t ws_size,
                              hipStream_t stream) {
  const float* in_graph = (const float*)d_in[0];
  const float* weights  = (const float*)d_in[1];
  const int*   fold_idx = (const int*)d_in[2];
  const int*   out_idx  = (const int*)d_in[3];
  float* out = (float*)d_out;

  char* ws   = (char*)d_ws;
  int*  tree = (int*)ws;                                           // 248 ints
  float* bufA = (float*)(ws + 4096);                               // 64 slots = 32 MB
  float* bufB = (float*)(ws + 4096 + (size_t)64 * BATCH * FD * 4); // 32 slots = 16 MB

  build_tree_kernel<<<1, 64, 0, stream>>>(fold_idx, out_idx, tree);

  // stage 1: 64 nodes, reads in_graph (T0 gather), writes bufA
  stage_kernel<0, T1_OFF, true,  false><<<64 * NBT, 256, 0, stream>>>(in_graph, weights, tree, bufA);
  // stage 2: 32 nodes, bufA -> bufB
  stage_kernel<1, T2_OFF, false, false><<<32 * NBT, 256, 0, stream>>>(bufA, weights, tree, bufB);
  // stage 3: 16 nodes, bufB -> bufA (stage-1 slots dead)
  stage_kernel<2, T3_OFF, false, false><<<16 * NBT, 256, 0, stream>>>(bufB, weights, tree, bufA);
  // stage 4: 8 nodes, bufA -> d_out
  stage_kernel<3, T4_OFF, false, true ><<< 8 * NBT, 256, 0, stream>>>(bufA, weights, tree, out);
}

// Round 3
// 376.590 us; speedup vs baseline: 1.3041x; 1.0418x over previous
//
#include <hip/hip_runtime.h>

#define BATCH 2048
#define NF 512
#define FD 64
#define BT 16                 // batch rows per block
#define SLOTF (16 * 17 * 4)   // floats per LDS slot: [kq=16][b=16+1pad][4]

// One block = (output o, batch tile of 16 rows). Entire 15-node subtree
// computed in-block; intermediates live in LDS only (zero HBM round-trip).
// Slot layout [kq][b][c] holds value[b][4*kq+c]; child k = parent j, so the
// same layout serves C-stores (j-indexed) and H-reads (k-indexed).
// Compute rows b = 4r+ty -> k-loop ds_read_b128 are conflict-free
// (4 banks x 16-lane broadcast). Staging/C-stores are 8-way but once/node.
__global__ __launch_bounds__(512) void fused_dag_kernel(
    const float* __restrict__ in_graph,
    const float* __restrict__ weights,
    const int* __restrict__ fold_idx,
    const int* __restrict__ out_idx,
    float* __restrict__ out) {
  __shared__ float bufA[8 * SLOTF];   // L1 outs; reused for L3 outs
  __shared__ float bufB[4 * SLOTF];   // L2 outs
  __shared__ int T[32];  // 0:F4 | 1..2:F3 | 3..6:F2 | 7..14:F1 | 15..30:F0

  const int o    = blockIdx.x & 7;
  const int tile = blockIdx.x >> 3;
  const int B0   = tile * BT;
  const int t    = threadIdx.x;

  // ---- per-block fold-table rebuild (5 dependent levels, L2-hot) ----
  if (t == 0) {
    int f4 = out_idx[o];
    T[0] = f4;
    T[1] = fold_idx[(3 * NF + f4) * 2 + 0];
    T[2] = fold_idx[(3 * NF + f4) * 2 + 1];
    #pragma unroll
    for (int i = 0; i < 2; ++i) {
      int f = T[1 + i];
      T[3 + 2 * i]     = fold_idx[(2 * NF + f) * 2 + 0];
      T[3 + 2 * i + 1] = fold_idx[(2 * NF + f) * 2 + 1];
    }
    #pragma unroll
    for (int i = 0; i < 4; ++i) {
      int f = T[3 + i];
      T[7 + 2 * i]     = fold_idx[(1 * NF + f) * 2 + 0];
      T[7 + 2 * i + 1] = fold_idx[(1 * NF + f) * 2 + 1];
    }
    #pragma unroll
    for (int i = 0; i < 8; ++i) {
      int f = T[7 + i];
      T[15 + 2 * i]     = fold_idx[(0 * NF + f) * 2 + 0];
      T[15 + 2 * i + 1] = fold_idx[(0 * NF + f) * 2 + 1];
    }
  }
  __syncthreads();

  const int w  = t >> 6;    // wave 0..7
  const int l  = t & 63;
  const int tx = l & 15;    // j-quad (cols 4*tx..+3)
  const int ty = l >> 4;    // 0..3

  // ================= stage 1: 8 nodes, 1 wave each =================
  {
    const int node = w;
    float* slot = bufA + node * SLOTF;
    const int f0 = T[15 + 2 * node];
    const int f1 = T[16 + 2 * node];
    // H = x[f0] (.) x[f1] staged into own output slot (k-fast lanes = coalesced)
    #pragma unroll
    for (int r = 0; r < 4; ++r) {
      const int b = ty * 4 + r;
      const float* row = in_graph + (size_t)(B0 + b) * NF * FD + tx * 4;
      float4 a = *(const float4*)(row + f0 * FD);
      float4 c = *(const float4*)(row + f1 * FD);
      float4 h;
      h.x = a.x * c.x; h.y = a.y * c.y; h.z = a.z * c.z; h.w = a.w * c.w;
      *(float4*)(slot + (tx * 17 + b) * 4) = h;
    }
    const float* W = weights + (size_t)(0 * NF + T[7 + node]) * (FD * FD);
    float4 acc[4];
    #pragma unroll
    for (int r = 0; r < 4; ++r) acc[r] = make_float4(0.f, 0.f, 0.f, 0.f);
    #pragma unroll 2
    for (int kq = 0; kq < 16; ++kq) {
      const float* Wk = W + kq * 4 * FD + tx * 4;
      float4 w0 = *(const float4*)(Wk);
      float4 w1 = *(const float4*)(Wk + FD);
      float4 w2 = *(const float4*)(Wk + 2 * FD);
      float4 w3 = *(const float4*)(Wk + 3 * FD);
      #pragma unroll
      for (int r = 0; r < 4; ++r) {
        float4 h = *(const float4*)(slot + (kq * 17 + 4 * r + ty) * 4);
        acc[r].x = fmaf(h.x, w0.x, acc[r].x); acc[r].y = fmaf(h.x, w0.y, acc[r].y);
        acc[r].z = fmaf(h.x, w0.z, acc[r].z); acc[r].w = fmaf(h.x, w0.w, acc[r].w);
        acc[r].x = fmaf(h.y, w1.x, acc[r].x); acc[r].y = fmaf(h.y, w1.y, acc[r].y);
        acc[r].z = fmaf(h.y, w1.z, acc[r].z); acc[r].w = fmaf(h.y, w1.w, acc[r].w);
        acc[r].x = fmaf(h.z, w2.x, acc[r].x); acc[r].y = fmaf(h.z, w2.y, acc[r].y);
        acc[r].z = fmaf(h.z, w2.z, acc[r].z); acc[r].w = fmaf(h.z, w2.w, acc[r].w);
        acc[r].x = fmaf(h.w, w3.x, acc[r].x); acc[r].y = fmaf(h.w, w3.y, acc[r].y);
        acc[r].z = fmaf(h.w, w3.z, acc[r].z); acc[r].w = fmaf(h.w, w3.w, acc[r].w);
      }
    }
    #pragma unroll
    for (int r = 0; r < 4; ++r)
      *(float4*)(slot + (tx * 17 + 4 * r + ty) * 4) = acc[r];
  }
  __syncthreads();

  // ================= stage 2: 4 nodes, 2 waves each =================
  {
    const int node = w >> 1, half = w & 1;
    const float* P0 = bufA + (2 * node) * SLOTF;
    const float* P1 = bufA + (2 * node + 1) * SLOTF;
    const float* W = weights + (size_t)(1 * NF + T[3 + node]) * (FD * FD);
    float* slot = bufB + node * SLOTF;
    float4 acc[2];
    acc[0] = make_float4(0.f, 0.f, 0.f, 0.f);
    acc[1] = make_float4(0.f, 0.f, 0.f, 0.f);
    #pragma unroll 2
    for (int kq = 0; kq < 16; ++kq) {
      const float* Wk = W + kq * 4 * FD + tx * 4;
      float4 w0 = *(const float4*)(Wk);
      float4 w1 = *(const float4*)(Wk + FD);
      float4 w2 = *(const float4*)(Wk + 2 * FD);
      float4 w3 = *(const float4*)(Wk + 3 * FD);
      #pragma unroll
      for (int r = 0; r < 2; ++r) {
        const int b = half * 8 + 4 * r + ty;
        float4 pa = *(const float4*)(P0 + (kq * 17 + b) * 4);
        float4 pb = *(const float4*)(P1 + (kq * 17 + b) * 4);
        float4 h;
        h.x = pa.x * pb.x; h.y = pa.y * pb.y; h.z = pa.z * pb.z; h.w = pa.w * pb.w;
        acc[r].x = fmaf(h.x, w0.x, acc[r].x); acc[r].y = fmaf(h.x, w0.y, acc[r].y);
        acc[r].z = fmaf(h.x, w0.z, acc[r].z); acc[r].w = fmaf(h.x, w0.w, acc[r].w);
        acc[r].x = fmaf(h.y, w1.x, acc[r].x); acc[r].y = fmaf(h.y, w1.y, acc[r].y);
        acc[r].z = fmaf(h.y, w1.z, acc[r].z); acc[r].w = fmaf(h.y, w1.w, acc[r].w);
        acc[r].x = fmaf(h.z, w2.x, acc[r].x); acc[r].y = fmaf(h.z, w2.y, acc[r].y);
        acc[r].z = fmaf(h.z, w2.z, acc[r].z); acc[r].w = fmaf(h.z, w2.w, acc[r].w);
        acc[r].x = fmaf(h.w, w3.x, acc[r].x); acc[r].y = fmaf(h.w, w3.y, acc[r].y);
        acc[r].z = fmaf(h.w, w3.z, acc[r].z); acc[r].w = fmaf(h.w, w3.w, acc[r].w);
      }
    }
    #pragma unroll
    for (int r = 0; r < 2; ++r)
      *(float4*)(slot + (tx * 17 + half * 8 + 4 * r + ty) * 4) = acc[r];
  }
  __syncthreads();

  // ================= stage 3: 2 nodes, 4 waves each =================
  {
    const int node = w >> 2, q = w & 3;
    const float* P0 = bufB + (2 * node) * SLOTF;
    const float* P1 = bufB + (2 * node + 1) * SLOTF;
    const float* W = weights + (size_t)(2 * NF + T[1 + node]) * (FD * FD);
    float* slot = bufA + node * SLOTF;   // bufA dead after stage 2
    const int b = q * 4 + ty;
    float4 acc = make_float4(0.f, 0.f, 0.f, 0.f);
    #pragma unroll 2
    for (int kq = 0; kq < 16; ++kq) {
      const float* Wk = W + kq * 4 * FD + tx * 4;
      float4 w0 = *(const float4*)(Wk);
      float4 w1 = *(const float4*)(Wk + FD);
      float4 w2 = *(const float4*)(Wk + 2 * FD);
      float4 w3 = *(const float4*)(Wk + 3 * FD);
      float4 pa = *(const float4*)(P0 + (kq * 17 + b) * 4);
      float4 pb = *(const float4*)(P1 + (kq * 17 + b) * 4);
      float4 h;
      h.x = pa.x * pb.x; h.y = pa.y * pb.y; h.z = pa.z * pb.z; h.w = pa.w * pb.w;
      acc.x = fmaf(h.x, w0.x, acc.x); acc.y = fmaf(h.x, w0.y, acc.y);
      acc.z = fmaf(h.x, w0.z, acc.z); acc.w = fmaf(h.x, w0.w, acc.w);
      acc.x = fmaf(h.y, w1.x, acc.x); acc.y = fmaf(h.y, w1.y, acc.y);
      acc.z = fmaf(h.y, w1.z, acc.z); acc.w = fmaf(h.y, w1.w, acc.w);
      acc.x = fmaf(h.z, w2.x, acc.x); acc.y = fmaf(h.z, w2.y, acc.y);
      acc.z = fmaf(h.z, w2.z, acc.z); acc.w = fmaf(h.z, w2.w, acc.w);
      acc.x = fmaf(h.w, w3.x, acc.x); acc.y = fmaf(h.w, w3.y, acc.y);
      acc.z = fmaf(h.w, w3.z, acc.z); acc.w = fmaf(h.w, w3.w, acc.w);
    }
    *(float4*)(slot + (tx * 17 + b) * 4) = acc;
  }
  __syncthreads();

  // ================= stage 4: 1 node, waves 0..3 =================
  if (w < 4) {
    const float* P0 = bufA + 0 * SLOTF;
    const float* P1 = bufA + 1 * SLOTF;
    const float* W = weights + (size_t)(3 * NF + T[0]) * (FD * FD);
    const int b = w * 4 + ty;
    float4 acc = make_float4(0.f, 0.f, 0.f, 0.f);
    #pragma unroll 2
    for (int kq = 0; kq < 16; ++kq) {
      const float* Wk = W + kq * 4 * FD + tx * 4;
      float4 w0 = *(const float4*)(Wk);
      float4 w1 = *(const float4*)(Wk + FD);
      float4 w2 = *(const float4*)(Wk + 2 * FD);
      float4 w3 = *(const float4*)(Wk + 3 * FD);
      float4 pa = *(const float4*)(P0 + (kq * 17 + b) * 4);
      float4 pb = *(const float4*)(P1 + (kq * 17 + b) * 4);
      float4 h;
      h.x = pa.x * pb.x; h.y = pa.y * pb.y; h.z = pa.z * pb.z; h.w = pa.w * pb.w;
      acc.x = fmaf(h.x, w0.x, acc.x); acc.y = fmaf(h.x, w0.y, acc.y);
      acc.z = fmaf(h.x, w0.z, acc.z); acc.w = fmaf(h.x, w0.w, acc.w);
      acc.x = fmaf(h.y, w1.x, acc.x); acc.y = fmaf(h.y, w1.y, acc.y);
      acc.z = fmaf(h.y, w1.z, acc.z); acc.w = fmaf(h.y, w1.w, acc.w);
      acc.x = fmaf(h.z, w2.x, acc.x); acc.y = fmaf(h.z, w2.y, acc.y);
      acc.z = fmaf(h.z, w2.z, acc.z); acc.w = fmaf(h.z, w2.w, acc.w);
      acc.x = fmaf(h.w, w3.x, acc.x); acc.y = fmaf(h.w, w3.y, acc.y);
      acc.z = fmaf(h.w, w3.z, acc.z); acc.w = fmaf(h.w, w3.w, acc.w);
    }
    // out[b][o][j], fp32
    *(float4*)(out + ((size_t)(B0 + b) * 8 + o) * FD + tx * 4) = acc;
  }
}

extern "C" void kernel_launch(void* const* d_in, const int* in_sizes, int n_in,
                              void* d_out, int out_size, void* d_ws, size_t ws_size,
                              hipStream_t stream) {
  const float* in_graph = (const float*)d_in[0];
  const float* weights  = (const float*)d_in[1];
  const int*   fold_idx = (const int*)d_in[2];
  const int*   out_idx  = (const int*)d_in[3];
  float* out = (float*)d_out;

  // grid: 8 outputs x 128 batch tiles of 16 rows; d_ws unused.
  fused_dag_kernel<<<(BATCH / BT) * 8, 512, 0, stream>>>(
      in_graph, weights, fold_idx, out_idx, out);
}